// Round 14
// baseline (118.951 us; speedup 1.0000x reference)
//
#include <hip/hip_runtime.h>
#include <hip/hip_bf16.h>
#include <math.h>

#define T_DIM 256
#define C_DIM 128
#define H_DIM 64

// d_ws layout (short units):
//  wt @0            : 24576 sh (48KB) bf16 W^T (Wq rows permuted + pre-scaled)
//  batch b @ WS_B + b*BATCH_SH:
//    Kp @+0         : 16384 sh (32KB) K row-permuted, 16B-slot XOR swizzle
//                     (byte-identical to the attention kernel's LDS image)
//    VT @+16384     : 16384 sh (32KB) V^T swizzled
//    Qf @+32768     : 16384 sh (32KB) packed Q MFMA fragments per (tile,lane)
#define WS_B 24576
#define BATCH_SH 49152
#define SMEM_BYTES 32768   // attn kernel: K only -> 4 blocks/CU

typedef __attribute__((ext_vector_type(8))) short short8v;
typedef __attribute__((ext_vector_type(4))) short short4v;
typedef __attribute__((ext_vector_type(4))) float float4v;

static __device__ __forceinline__ short f2bf(float f) {
  union { float f; unsigned u; } x; x.f = f;
  unsigned r = x.u + 0x7FFFu + ((x.u >> 16) & 1u);  // RNE
  return (short)(r >> 16);
}
static __device__ __forceinline__ unsigned pk2bf(float lo, float hi) {
  union { __hip_bfloat162 h; unsigned u; } cv;
  cv.h = __float22bfloat162_rn(make_float2(lo, hi));
  return cv.u;
}
static __device__ __forceinline__ short8v mk8(unsigned w0, unsigned w1,
                                              unsigned w2, unsigned w3) {
  union { short8v s; unsigned u[4]; } r;
  r.u[0] = w0; r.u[1] = w1; r.u[2] = w2; r.u[3] = w3;
  return r.s;
}
static __device__ __forceinline__ short4v mk4(unsigned w0, unsigned w1) {
  union { short4v s; unsigned u[2]; } r;
  r.u[0] = w0; r.u[1] = w1;
  return r.s;
}

// storage-row permutation within a 64-row block:
// row' such that QK^T D-layout delivers J = (jt&1)*32 + g*8 + (jt>>1)*4 + r
static __device__ __forceinline__ int permrow(int J) {
  return ((J >> 5) + ((J >> 2) & 1) * 2) * 16 + (((J >> 3) & 3) << 2) + (J & 3);
}
static __device__ __forceinline__ int kaddr(int row, int col) {
  return row * 64 + ((((col >> 3) ^ (row & 7))) << 3) + (col & 7);
}
static __device__ __forceinline__ int vaddr(int h, int t) {
  return h * 256 + ((((t >> 3) ^ (h & 7))) << 3) + (t & 7);
}

#define MFMA_BF16 __builtin_amdgcn_mfma_f32_16x16x32_bf16

// prep: W[c][h] f32 -> wt[p][h][c] bf16. Q rows permuted + pre-scaled.
__global__ void prep_w(const float* __restrict__ Wq, const float* __restrict__ Wk,
                       const float* __restrict__ Wv, short* __restrict__ wt) {
  const float SCL2 = 0.12751744f;  // C^-0.5 * log2(e) folded into Wq
  int t = blockIdx.x * 256 + threadIdx.x;
  int p = t >> 11;
  int i4 = t & 2047;
  const float* W = (p == 0) ? Wq : (p == 1) ? Wk : Wv;
  float4v v = *(const float4v*)(W + i4 * 4);
  if (p == 0) { v.x *= SCL2; v.y *= SCL2; v.z *= SCL2; v.w *= SCL2; }
  int c = i4 >> 4;
  int h0 = (i4 & 15) * 4;
  float vv[4] = {v.x, v.y, v.z, v.w};
#pragma unroll
  for (int j = 0; j < 4; ++j) {
    int h = h0 + j;
    int hr = (p == 0) ? permrow(h) : h;
    wt[p * 8192 + hr * 128 + c] = f2bf(vv[j]);
  }
}

// ---------------- kernel 1: QKV projection (streaming, no LDS) ----------------
// R10's phase-1 with global destinations. 4 blocks/CU resident (no LDS),
// 8 waves/SIMD -> memory stays saturated.
__global__ __launch_bounds__(512) void qkv_proj(
    const float* __restrict__ x, short* __restrict__ ws)
{
  const int b   = blockIdx.x;
  const int tid = threadIdx.x;
  const int w   = tid >> 6;
  const int l   = tid & 63;
  const int il  = l & 15;
  const int g   = l >> 4;
  int tqs[2]; tqs[0] = w; tqs[1] = 15 - w;

  const short* wt = ws;
  short* Kp = ws + WS_B + (size_t)b * BATCH_SH;
  short* VT = Kp + 16384;
  short* Qf = Kp + 32768;

  // x load + convert
  short8v xa[2][4];
  {
    const float* xb = x + (size_t)b * (T_DIM * C_DIM);
#pragma unroll
    for (int tt = 0; tt < 2; ++tt)
#pragma unroll
      for (int ks = 0; ks < 4; ++ks) {
        const float* src = xb + (tqs[tt] * 16 + il) * C_DIM + ks * 32 + g * 8;
        float4v a0 = *(const float4v*)src;
        float4v a1 = *(const float4v*)(src + 4);
        xa[tt][ks] = mk8(pk2bf(a0.x, a0.y), pk2bf(a0.z, a0.w),
                         pk2bf(a1.x, a1.y), pk2bf(a1.z, a1.w));
      }
  }

  // 12 steps: p = idx>>2 (0=Q,1=K,2=V), ht = idx&3; W double-buffered
  float4v accQ[2][4];
  short8v wb[2][4];
#pragma unroll
  for (int ks = 0; ks < 4; ++ks)
    wb[0][ks] = *(const short8v*)(wt + il * 128 + ks * 32 + g * 8);
#pragma unroll
  for (int idx = 0; idx < 12; ++idx) {
    const int p   = idx >> 2, ht = idx & 3;
    const int cur = idx & 1,  nxt = cur ^ 1;
    if (idx < 11) {
      const int p2 = (idx + 1) >> 2, ht2 = (idx + 1) & 3;
#pragma unroll
      for (int ks = 0; ks < 4; ++ks)
        wb[nxt][ks] = *(const short8v*)(wt + (p2 * 64 + ht2 * 16 + il) * 128 + ks * 32 + g * 8);
    }
#pragma unroll
    for (int tt = 0; tt < 2; ++tt) {
      float4v acc = {0.f, 0.f, 0.f, 0.f};
      const int tq = tqs[tt];
      if (p == 0) {
        // Q^T = Wq^T_perm . x^T (W as A-frag) -> accQ in registers
#pragma unroll
        for (int ks = 0; ks < 4; ++ks)
          acc = MFMA_BF16(wb[cur][ks], xa[tt][ks], acc, 0, 0, 0);
        accQ[tt][ht] = acc;
      } else {
#pragma unroll
        for (int ks = 0; ks < 4; ++ks)
          acc = MFMA_BF16(xa[tt][ks], wb[cur][ks], acc, 0, 0, 0);
        if (p == 1) {
          // K stored row-permuted: t = tq*16+g*4+r -> (t>>6)*64 + permrow(t&63)
          int row0 = (tq >> 2) * 64 + (((tq & 3) >> 1) + ((g & 1) << 1)) * 16
                   + (((((tq & 3) << 1) + (g >> 1)) & 3) << 2);
          int col = ht * 16 + il;
#pragma unroll
          for (int r = 0; r < 4; ++r)
            Kp[kaddr(row0 + r, col)] = f2bf(acc[r]);
        } else {
          *(short4v*)&VT[vaddr(ht * 16 + il, tq * 16 + g * 4)] =
              mk4(pk2bf(acc[0], acc[1]), pk2bf(acc[2], acc[3]));
        }
      }
    }
    if (idx == 3) {
      // pack qf and store to Qf: tile tq, lane l, hk -> [tq*1024 + hk*512 + l*8]
#pragma unroll
      for (int tt = 0; tt < 2; ++tt)
#pragma unroll
        for (int hk = 0; hk < 2; ++hk) {
          short8v q = mk8(pk2bf(accQ[tt][hk][0],     accQ[tt][hk][1]),
                          pk2bf(accQ[tt][hk][2],     accQ[tt][hk][3]),
                          pk2bf(accQ[tt][hk + 2][0], accQ[tt][hk + 2][1]),
                          pk2bf(accQ[tt][hk + 2][2], accQ[tt][hk + 2][3]));
          *(short8v*)&Qf[tqs[tt] * 1024 + hk * 512 + l * 8] = q;
        }
    }
  }
}

// ---------------- kernel 2: attention (K in LDS, V/Q from L2/L3) ----------------
// streaming no-max softmax for one 16-query tile; scores in log2 domain
// (scale folded into Wq); |s_log2| <~ 8 -> exp2 <~ 400, f32-safe.
template<int NB, bool SK>
static __device__ __forceinline__ void attn_tile(
    const short* sm, const short* __restrict__ vt, const short8v* qf,
    int il, int g, int tq, float4v* oa)
{
  const int i_row = tq * 16 + il;
  const int c0 = (g ^ (il & 7)) << 3;
  const int c1 = ((4 + g) ^ (il & 7)) << 3;
  float lr = 0.f;
#pragma unroll
  for (int jb = 0; jb < NB; ++jb) {
    const bool diag = (jb == NB - 1);
    float s[4][4];
    __builtin_amdgcn_s_setprio(1);
#pragma unroll
    for (int jt = 0; jt < 4; ++jt) {
      if (SK && diag && (jt & 1)) continue;
      const int rb = jb * 64 + jt * 16 + il;
      short8v kf0 = *(const short8v*)&sm[rb * 64 + c0];
      short8v kf1 = *(const short8v*)&sm[rb * 64 + c1];
      float4v a = {0.f, 0.f, 0.f, 0.f};
      a = MFMA_BF16(kf0, qf[0], a, 0, 0, 0);
      a = MFMA_BF16(kf1, qf[1], a, 0, 0, 0);
      s[jt][0] = a[0]; s[jt][1] = a[1]; s[jt][2] = a[2]; s[jt][3] = a[3];
    }
    __builtin_amdgcn_s_setprio(0);
    // V half-0 fragments from global (L2/L3-resident; arrive during exp)
    short8v vf0[4];
    {
      const int sl = ((jb * 8 + g) ^ (il & 7)) << 3;
#pragma unroll
      for (int ht = 0; ht < 4; ++ht)
        vf0[ht] = *(const short8v*)&vt[(ht * 16 + il) * 256 + sl];
    }
    // exp2 (no max pass) + causal zero on diag + lane-local sum
#pragma unroll
    for (int jt = 0; jt < 4; ++jt) {
      if (SK && diag && (jt & 1)) continue;
      const int j0 = jb * 64 + ((jt & 1) << 5) + (g << 3) + ((jt >> 1) << 2);
#pragma unroll
      for (int r = 0; r < 4; ++r) {
        float pv = exp2f(s[jt][r]);
        if (diag && (j0 + r > i_row)) pv = 0.f;
        s[jt][r] = pv;
        lr += pv;
      }
    }
    // V half-1: issue before PV0 so they arrive under its MFMAs
    short8v vf1[4];
    if (!(SK && diag)) {
      const int sl1 = ((jb * 8 + 4 + g) ^ (il & 7)) << 3;
#pragma unroll
      for (int ht = 0; ht < 4; ++ht)
        vf1[ht] = *(const short8v*)&vt[(ht * 16 + il) * 256 + sl1];
    }
    __builtin_amdgcn_s_setprio(1);
    {
      short8v pf = mk8(pk2bf(s[0][0], s[0][1]), pk2bf(s[0][2], s[0][3]),
                       pk2bf(s[2][0], s[2][1]), pk2bf(s[2][2], s[2][3]));
#pragma unroll
      for (int ht = 0; ht < 4; ++ht)
        oa[ht] = MFMA_BF16(vf0[ht], pf, oa[ht], 0, 0, 0);
    }
    if (!(SK && diag)) {
      short8v pf = mk8(pk2bf(s[1][0], s[1][1]), pk2bf(s[1][2], s[1][3]),
                       pk2bf(s[3][0], s[3][1]), pk2bf(s[3][2], s[3][3]));
#pragma unroll
      for (int ht = 0; ht < 4; ++ht)
        oa[ht] = MFMA_BF16(vf1[ht], pf, oa[ht], 0, 0, 0);
    }
    __builtin_amdgcn_s_setprio(0);
  }
  lr += __shfl_xor(lr, 16);
  lr += __shfl_xor(lr, 32);
  const float inv = 1.f / lr;
#pragma unroll
  for (int ht = 0; ht < 4; ++ht) oa[ht] *= inv;
}

__global__ __launch_bounds__(512) void attn_k(
    const short* __restrict__ ws, float* __restrict__ out)
{
  extern __shared__ __align__(16) short sm[];   // 32KB: K image
  const int b   = blockIdx.x;
  const int tid = threadIdx.x;
  const int w   = tid >> 6;
  const int l   = tid & 63;
  const int il  = l & 15;
  const int g   = l >> 4;
  int tqs[2]; tqs[0] = w; tqs[1] = 15 - w;

  const short* Kp = ws + WS_B + (size_t)b * BATCH_SH;
  const short* VT = Kp + 16384;
  const short* Qf = Kp + 32768;

  // qf loads (global, independent of LDS -> hide under barrier)
  short8v qf[2][2];
#pragma unroll
  for (int tt = 0; tt < 2; ++tt) {
    qf[tt][0] = *(const short8v*)&Qf[tqs[tt] * 1024 + l * 8];
    qf[tt][1] = *(const short8v*)&Qf[tqs[tt] * 1024 + 512 + l * 8];
  }
  // stage K: linear 32KB copy (ws image == LDS image), coalesced b128
#pragma unroll
  for (int i = 0; i < 4; ++i) {
    short8v v = *(const short8v*)&Kp[tid * 8 + i * 4096];
    *(short8v*)&sm[tid * 8 + i * 4096] = v;
  }
  __syncthreads();

  float* outb = out + (size_t)b * (T_DIM * H_DIM);
#pragma unroll
  for (int tt = 0; tt < 2; ++tt) {
    const int tq = tqs[tt];
    float4v oa[4];
#pragma unroll
    for (int ht = 0; ht < 4; ++ht) { float4v z = {0.f,0.f,0.f,0.f}; oa[ht] = z; }
    const bool sk = (tq & 3) < 2;
    if (tt == 0) {   // nb in {1,2}
      if (tq < 4) { if (sk) attn_tile<1, true>(sm, VT, qf[0], il, g, tq, oa);
                    else    attn_tile<1, false>(sm, VT, qf[0], il, g, tq, oa); }
      else        { if (sk) attn_tile<2, true>(sm, VT, qf[0], il, g, tq, oa);
                    else    attn_tile<2, false>(sm, VT, qf[0], il, g, tq, oa); }
    } else {         // nb in {3,4}
      if (tq < 12) { if (sk) attn_tile<3, true>(sm, VT, qf[1], il, g, tq, oa);
                     else    attn_tile<3, false>(sm, VT, qf[1], il, g, tq, oa); }
      else         { if (sk) attn_tile<4, true>(sm, VT, qf[1], il, g, tq, oa);
                     else    attn_tile<4, false>(sm, VT, qf[1], il, g, tq, oa); }
    }
    // direct stores: lane holds O[t = tq*16+il][h = ht*16 + g*4 .. +3]
#pragma unroll
    for (int ht = 0; ht < 4; ++ht)
      *(float4v*)&outb[(tq * 16 + il) * H_DIM + ht * 16 + g * 4] = oa[ht];
  }
}

extern "C" void kernel_launch(void* const* d_in, const int* in_sizes, int n_in,
                              void* d_out, int out_size, void* d_ws, size_t ws_size,
                              hipStream_t stream) {
  const float* x  = (const float*)d_in[0];
  const float* Wq = (const float*)d_in[1];
  const float* Wk = (const float*)d_in[2];
  const float* Wv = (const float*)d_in[3];
  float* out = (float*)d_out;
  short* ws = (short*)d_ws;   // 48KB wt + 96MB QKV
  prep_w<<<dim3(24), dim3(256), 0, stream>>>(Wq, Wk, Wv, ws);
  qkv_proj<<<dim3(1024), dim3(512), 0, stream>>>(x, ws);
  (void)hipFuncSetAttribute((const void*)attn_k,
                      hipFuncAttributeMaxDynamicSharedMemorySize, SMEM_BYTES);
  attn_k<<<dim3(1024), dim3(512), SMEM_BYTES, stream>>>(ws, out);
}

// Round 15
// 115.391 us; speedup vs baseline: 1.0308x; 1.0308x over previous
//
#include <hip/hip_runtime.h>
#include <hip/hip_bf16.h>
#include <math.h>

#define T_DIM 256
#define C_DIM 128
#define H_DIM 64

// LDS: K image ONLY [256][64] bf16 (32KB, rows permuted, 16B-slot XOR swizzle)
//  -> up to 4 blocks/CU (thread cap), double R10's TLP.
// V^T lives in global d_ws (unswizzled [64][256] per batch), L2-resident.
#define SMEM_BYTES 32768
#define WT_SH 24576            // wt size in shorts
#define VT_SH 16384            // per-batch VT shorts

typedef __attribute__((ext_vector_type(8))) short short8v;
typedef __attribute__((ext_vector_type(4))) short short4v;
typedef __attribute__((ext_vector_type(4))) float float4v;

static __device__ __forceinline__ short f2bf(float f) {
  union { float f; unsigned u; } x; x.f = f;
  unsigned r = x.u + 0x7FFFu + ((x.u >> 16) & 1u);  // RNE
  return (short)(r >> 16);
}
static __device__ __forceinline__ unsigned pk2bf(float lo, float hi) {
  union { __hip_bfloat162 h; unsigned u; } cv;
  cv.h = __float22bfloat162_rn(make_float2(lo, hi));
  return cv.u;
}
static __device__ __forceinline__ short8v mk8(unsigned w0, unsigned w1,
                                              unsigned w2, unsigned w3) {
  union { short8v s; unsigned u[4]; } r;
  r.u[0] = w0; r.u[1] = w1; r.u[2] = w2; r.u[3] = w3;
  return r.s;
}
static __device__ __forceinline__ short4v mk4(unsigned w0, unsigned w1) {
  union { short4v s; unsigned u[2]; } r;
  r.u[0] = w0; r.u[1] = w1;
  return r.s;
}

// storage-row permutation within a 64-row block:
// row' such that QK^T D-layout delivers J = (jt&1)*32 + g*8 + (jt>>1)*4 + r
static __device__ __forceinline__ int permrow(int J) {
  return ((J >> 5) + ((J >> 2) & 1) * 2) * 16 + (((J >> 3) & 3) << 2) + (J & 3);
}
static __device__ __forceinline__ int kaddr(int row, int col) {
  return row * 64 + ((((col >> 3) ^ (row & 7))) << 3) + (col & 7);
}

#define MFMA_BF16 __builtin_amdgcn_mfma_f32_16x16x32_bf16

// prep: W[c][h] f32 -> wt[p][h][c] bf16 (48KB in d_ws). Q rows permuted + pre-scaled.
__global__ void prep_w(const float* __restrict__ Wq, const float* __restrict__ Wk,
                       const float* __restrict__ Wv, short* __restrict__ wt) {
  const float SCL2 = 0.12751744f;  // C^-0.5 * log2(e) folded into Wq
  int t = blockIdx.x * 256 + threadIdx.x;
  int p = t >> 11;
  int i4 = t & 2047;
  const float* W = (p == 0) ? Wq : (p == 1) ? Wk : Wv;
  float4v v = *(const float4v*)(W + i4 * 4);
  if (p == 0) { v.x *= SCL2; v.y *= SCL2; v.z *= SCL2; v.w *= SCL2; }
  int c = i4 >> 4;
  int h0 = (i4 & 15) * 4;
  float vv[4] = {v.x, v.y, v.z, v.w};
#pragma unroll
  for (int j = 0; j < 4; ++j) {
    int h = h0 + j;
    int hr = (p == 0) ? permrow(h) : h;
    wt[p * 8192 + hr * 128 + c] = f2bf(vv[j]);
  }
}

// streaming no-max softmax attention for one 16-query tile.
// K from LDS (swizzled); V from global VT (unswizzled, same-block L2-resident).
// Scores in log2 domain (scale folded into Wq); no max pass needed
// (|s_log2| <~ 8 -> exp2 <~ 400, f32-safe; softmax normalizes).
template<int NB, bool SK>
static __device__ __forceinline__ void attn_tile(
    const short* sm, const short* __restrict__ vt, const short8v* qf,
    int il, int g, int tq, float4v* oa)
{
  const int i_row = tq * 16 + il;
  const int c0 = (g ^ (il & 7)) << 3;
  const int c1 = ((4 + g) ^ (il & 7)) << 3;
  float lr = 0.f;
#pragma unroll
  for (int jb = 0; jb < NB; ++jb) {
    const bool diag = (jb == NB - 1);          // folds at compile time
    float s[4][4];
    __builtin_amdgcn_s_setprio(1);
#pragma unroll
    for (int jt = 0; jt < 4; ++jt) {
      if (SK && diag && (jt & 1)) continue;
      const int rb = jb * 64 + jt * 16 + il;
      short8v kf0 = *(const short8v*)&sm[rb * 64 + c0];
      short8v kf1 = *(const short8v*)&sm[rb * 64 + c1];
      float4v a = {0.f, 0.f, 0.f, 0.f};
      a = MFMA_BF16(kf0, qf[0], a, 0, 0, 0);
      a = MFMA_BF16(kf1, qf[1], a, 0, 0, 0);
      s[jt][0] = a[0]; s[jt][1] = a[1]; s[jt][2] = a[2]; s[jt][3] = a[3];
    }
    __builtin_amdgcn_s_setprio(0);
    // V half-0 fragments from global/L2 (independent of s; arrive during exp)
    short8v vf0[4];
    {
      const int cb = jb * 64 + g * 8;
#pragma unroll
      for (int ht = 0; ht < 4; ++ht)
        vf0[ht] = *(const short8v*)&vt[(ht * 16 + il) * 256 + cb];
    }
    // exp2 (no max pass) + causal zero on diag + lane-local sum
#pragma unroll
    for (int jt = 0; jt < 4; ++jt) {
      if (SK && diag && (jt & 1)) continue;
      const int j0 = jb * 64 + ((jt & 1) << 5) + (g << 3) + ((jt >> 1) << 2);
#pragma unroll
      for (int r = 0; r < 4; ++r) {
        float pv = exp2f(s[jt][r]);
        if (diag && (j0 + r > i_row)) pv = 0.f;
        s[jt][r] = pv;
        lr += pv;
      }
    }
    // V half-1: issue before PV0 so they arrive under its MFMAs
    short8v vf1[4];
    if (!(SK && diag)) {
      const int cb1 = jb * 64 + 32 + g * 8;
#pragma unroll
      for (int ht = 0; ht < 4; ++ht)
        vf1[ht] = *(const short8v*)&vt[(ht * 16 + il) * 256 + cb1];
    }
    __builtin_amdgcn_s_setprio(1);
    {
      short8v pf = mk8(pk2bf(s[0][0], s[0][1]), pk2bf(s[0][2], s[0][3]),
                       pk2bf(s[2][0], s[2][1]), pk2bf(s[2][2], s[2][3]));
#pragma unroll
      for (int ht = 0; ht < 4; ++ht)
        oa[ht] = MFMA_BF16(vf0[ht], pf, oa[ht], 0, 0, 0);
    }
    if (!(SK && diag)) {
      short8v pf = mk8(pk2bf(s[1][0], s[1][1]), pk2bf(s[1][2], s[1][3]),
                       pk2bf(s[3][0], s[3][1]), pk2bf(s[3][2], s[3][3]));
#pragma unroll
      for (int ht = 0; ht < 4; ++ht)
        oa[ht] = MFMA_BF16(vf1[ht], pf, oa[ht], 0, 0, 0);
    }
    __builtin_amdgcn_s_setprio(0);
  }
  lr += __shfl_xor(lr, 16);
  lr += __shfl_xor(lr, 32);
  const float inv = 1.f / lr;
#pragma unroll
  for (int ht = 0; ht < 4; ++ht) oa[ht] *= inv;
}

__global__ __launch_bounds__(512) void head_fused(
    const float* __restrict__ x, short* __restrict__ ws,
    float* __restrict__ out)
{
  extern __shared__ __align__(16) short sm[];   // 32KB: K image only
  const int b   = blockIdx.x;
  const int tid = threadIdx.x;
  const int w   = tid >> 6;
  const int l   = tid & 63;
  const int il  = l & 15;
  const int g   = l >> 4;

  int tqs[2]; tqs[0] = w; tqs[1] = 15 - w;   // balanced causal work

  const short* wt = ws;
  short* VTb = ws + WT_SH + (size_t)b * VT_SH;   // this batch's V^T [64][256]

  // ---------- x load + convert ----------
  short8v xa[2][4];
  {
    const float* xb = x + (size_t)b * (T_DIM * C_DIM);
#pragma unroll
    for (int tt = 0; tt < 2; ++tt)
#pragma unroll
      for (int ks = 0; ks < 4; ++ks) {
        const float* src = xb + (tqs[tt] * 16 + il) * C_DIM + ks * 32 + g * 8;
        float4v a0 = *(const float4v*)src;
        float4v a1 = *(const float4v*)(src + 4);
        xa[tt][ks] = mk8(pk2bf(a0.x, a0.y), pk2bf(a0.z, a0.w),
                         pk2bf(a1.x, a1.y), pk2bf(a1.z, a1.w));
      }
  }

  // ---------- phase 1: projections (12 steps, W double-buffered) ----------
  // step order: Q ht={0,2,1,3} (pairs pack immediately -> fewer live accs),
  // then K ht=0..3 (LDS), then V ht=0..3 (global VT).
  short8v qf[2][2];
  {
    const int wrow[12] = {0, 32, 16, 48, 64, 80, 96, 112, 128, 144, 160, 176};
    float4v accS[2];               // first-of-pair Q accs (per tile)
    short8v wb[2][4];
#pragma unroll
    for (int ks = 0; ks < 4; ++ks)
      wb[0][ks] = *(const short8v*)(wt + (wrow[0] + il) * 128 + ks * 32 + g * 8);
#pragma unroll
    for (int s = 0; s < 12; ++s) {
      const int cur = s & 1, nxt = cur ^ 1;
      if (s < 11) {
#pragma unroll
        for (int ks = 0; ks < 4; ++ks)
          wb[nxt][ks] = *(const short8v*)(wt + (wrow[s + 1] + il) * 128 + ks * 32 + g * 8);
      }
      if (s < 4) {
        // Q step (swapped operands; W as A-frag): pair = s>>1, d = s&1
#pragma unroll
        for (int tt = 0; tt < 2; ++tt) {
          float4v acc = {0.f, 0.f, 0.f, 0.f};
#pragma unroll
          for (int ks = 0; ks < 4; ++ks)
            acc = MFMA_BF16(wb[cur][ks], xa[tt][ks], acc, 0, 0, 0);
          if ((s & 1) == 0) {
            accS[tt] = acc;
          } else {
            qf[tt][s >> 1] = mk8(pk2bf(accS[tt][0], accS[tt][1]),
                                 pk2bf(accS[tt][2], accS[tt][3]),
                                 pk2bf(acc[0], acc[1]),
                                 pk2bf(acc[2], acc[3]));
          }
        }
      } else {
        const int p  = (s < 8) ? 1 : 2;
        const int ht = (s - 4) & 3;
#pragma unroll
        for (int tt = 0; tt < 2; ++tt) {
          float4v acc = {0.f, 0.f, 0.f, 0.f};
#pragma unroll
          for (int ks = 0; ks < 4; ++ks)
            acc = MFMA_BF16(xa[tt][ks], wb[cur][ks], acc, 0, 0, 0);
          const int tq = tqs[tt];
          if (p == 1) {
            // K -> LDS, row-permuted: t = tq*16+g*4+r -> (t>>6)*64 + permrow(t&63)
            int row0 = (tq >> 2) * 64 + (((tq & 3) >> 1) + ((g & 1) << 1)) * 16
                     + (((((tq & 3) << 1) + (g >> 1)) & 3) << 2);
            int col = ht * 16 + il;
#pragma unroll
            for (int r = 0; r < 4; ++r)
              sm[kaddr(row0 + r, col)] = f2bf(acc[r]);
          } else {
            // V -> global VT[h][t] unswizzled; 4 consecutive t per lane (8B),
            // g-neighbors merge to 32B segments
            *(short4v*)&VTb[(ht * 16 + il) * 256 + tq * 16 + g * 4] =
                mk4(pk2bf(acc[0], acc[1]), pk2bf(acc[2], acc[3]));
          }
        }
      }
    }
  }
  __syncthreads();   // K visible in LDS; VT global writes drained (vmcnt0+barrier)

  float* outb = out + (size_t)b * (T_DIM * H_DIM);

  // ---------- phase 2: attention + direct stores ----------
#pragma unroll
  for (int tt = 0; tt < 2; ++tt) {
    const int tq = tqs[tt];
    float4v oa[4];
#pragma unroll
    for (int ht = 0; ht < 4; ++ht) { float4v z = {0.f,0.f,0.f,0.f}; oa[ht] = z; }
    const bool sk = (tq & 3) < 2;
    if (tt == 0) {   // nb in {1,2}
      if (tq < 4) { if (sk) attn_tile<1, true>(sm, VTb, qf[0], il, g, tq, oa);
                    else    attn_tile<1, false>(sm, VTb, qf[0], il, g, tq, oa); }
      else        { if (sk) attn_tile<2, true>(sm, VTb, qf[0], il, g, tq, oa);
                    else    attn_tile<2, false>(sm, VTb, qf[0], il, g, tq, oa); }
    } else {         // nb in {3,4}
      if (tq < 12) { if (sk) attn_tile<3, true>(sm, VTb, qf[1], il, g, tq, oa);
                     else    attn_tile<3, false>(sm, VTb, qf[1], il, g, tq, oa); }
      else         { if (sk) attn_tile<4, true>(sm, VTb, qf[1], il, g, tq, oa);
                     else    attn_tile<4, false>(sm, VTb, qf[1], il, g, tq, oa); }
    }
    // direct stores: lane holds O[t = tq*16+il][h = ht*16 + g*4 .. +3]
#pragma unroll
    for (int ht = 0; ht < 4; ++ht)
      *(float4v*)&outb[(tq * 16 + il) * H_DIM + ht * 16 + g * 4] = oa[ht];
  }
}

extern "C" void kernel_launch(void* const* d_in, const int* in_sizes, int n_in,
                              void* d_out, int out_size, void* d_ws, size_t ws_size,
                              hipStream_t stream) {
  const float* x  = (const float*)d_in[0];
  const float* Wq = (const float*)d_in[1];
  const float* Wk = (const float*)d_in[2];
  const float* Wv = (const float*)d_in[3];
  float* out = (float*)d_out;
  short* ws = (short*)d_ws;   // 48KB wt + 32MB VT pool
  prep_w<<<dim3(24), dim3(256), 0, stream>>>(Wq, Wk, Wv, ws);
  (void)hipFuncSetAttribute((const void*)head_fused,
                      hipFuncAttributeMaxDynamicSharedMemorySize, SMEM_BYTES);
  head_fused<<<dim3(1024), dim3(512), SMEM_BYTES, stream>>>(x, ws, out);
}

// Round 16
// 50.578 us; speedup vs baseline: 2.3518x; 2.2815x over previous
//
#include <hip/hip_runtime.h>
#include <hip/hip_bf16.h>
#include <math.h>

#define T_DIM 256
#define C_DIM 128
#define H_DIM 64

// LDS (shorts), region-reuse plan (peak 80 KB = 2 blocks/CU exactly):
//   [0:24576)       W^T bf16 staged (48KB), 16B-slot XOR-swizzled by row&7
//                   Q-rows [0:8192) die after Q steps; K-rows [8192:16384)
//                   die after K steps; V-rows [16384:24576) die last.
//   [24576:40960)   K image (32KB, row-permuted + slot swizzle)  [lives to end]
//   [0:16384)       VT [64][256] swizzled (32KB) -- overwrites dead Q/K weights
#define K_OFF 24576
#define VT_OFF 0
#define SMEM_BYTES 81920

typedef __attribute__((ext_vector_type(8))) short short8v;
typedef __attribute__((ext_vector_type(4))) short short4v;
typedef __attribute__((ext_vector_type(4))) float float4v;

static __device__ __forceinline__ short f2bf(float f) {
  union { float f; unsigned u; } x; x.f = f;
  unsigned r = x.u + 0x7FFFu + ((x.u >> 16) & 1u);  // RNE
  return (short)(r >> 16);
}
static __device__ __forceinline__ unsigned pk2bf(float lo, float hi) {
  union { __hip_bfloat162 h; unsigned u; } cv;
  cv.h = __float22bfloat162_rn(make_float2(lo, hi));
  return cv.u;
}
static __device__ __forceinline__ short8v mk8(unsigned w0, unsigned w1,
                                              unsigned w2, unsigned w3) {
  union { short8v s; unsigned u[4]; } r;
  r.u[0] = w0; r.u[1] = w1; r.u[2] = w2; r.u[3] = w3;
  return r.s;
}
static __device__ __forceinline__ short4v mk4(unsigned w0, unsigned w1) {
  union { short4v s; unsigned u[2]; } r;
  r.u[0] = w0; r.u[1] = w1;
  return r.s;
}

// storage-row permutation within a 64-row block:
// row' such that QK^T D-layout delivers J = (jt&1)*32 + g*8 + (jt>>1)*4 + r
static __device__ __forceinline__ int permrow(int J) {
  return ((J >> 5) + ((J >> 2) & 1) * 2) * 16 + (((J >> 3) & 3) << 2) + (J & 3);
}
static __device__ __forceinline__ int kaddr(int row, int col) {
  return row * 64 + ((((col >> 3) ^ (row & 7))) << 3) + (col & 7);
}
static __device__ __forceinline__ int vaddr(int h, int t) {
  return h * 256 + ((((t >> 3) ^ (h & 7))) << 3) + (t & 7);
}

#define MFMA_BF16 __builtin_amdgcn_mfma_f32_16x16x32_bf16

// prep: W[c][h] f32 -> wt[p][h][c] bf16 (48KB in d_ws). Q rows permuted + pre-scaled.
__global__ void prep_w(const float* __restrict__ Wq, const float* __restrict__ Wk,
                       const float* __restrict__ Wv, short* __restrict__ wt) {
  const float SCL2 = 0.12751744f;  // C^-0.5 * log2(e) folded into Wq
  int t = blockIdx.x * 256 + threadIdx.x;
  int p = t >> 11;
  int i4 = t & 2047;
  const float* W = (p == 0) ? Wq : (p == 1) ? Wk : Wv;
  float4v v = *(const float4v*)(W + i4 * 4);
  if (p == 0) { v.x *= SCL2; v.y *= SCL2; v.z *= SCL2; v.w *= SCL2; }
  int c = i4 >> 4;
  int h0 = (i4 & 15) * 4;
  float vv[4] = {v.x, v.y, v.z, v.w};
#pragma unroll
  for (int j = 0; j < 4; ++j) {
    int h = h0 + j;
    int hr = (p == 0) ? permrow(h) : h;
    wt[p * 8192 + hr * 128 + c] = f2bf(vv[j]);
  }
}

// streaming no-max softmax attention for one 16-query tile (R10 verbatim,
// offsets only). Scores in log2 domain; no max pass (|s_log2| <~ 8).
template<int NB, bool SK>
static __device__ __forceinline__ void attn_tile(
    const short* sm, const short8v* qf, int il, int g, int tq, float4v* oa)
{
  const int i_row = tq * 16 + il;
  const int c0 = (g ^ (il & 7)) << 3;
  const int c1 = ((4 + g) ^ (il & 7)) << 3;
  float lr = 0.f;
#pragma unroll
  for (int jb = 0; jb < NB; ++jb) {
    const bool diag = (jb == NB - 1);
    float s[4][4];
    __builtin_amdgcn_s_setprio(1);
#pragma unroll
    for (int jt = 0; jt < 4; ++jt) {
      if (SK && diag && (jt & 1)) continue;
      const int rb = jb * 64 + jt * 16 + il;
      short8v kf0 = *(const short8v*)&sm[K_OFF + rb * 64 + c0];
      short8v kf1 = *(const short8v*)&sm[K_OFF + rb * 64 + c1];
      float4v a = {0.f, 0.f, 0.f, 0.f};
      a = MFMA_BF16(kf0, qf[0], a, 0, 0, 0);
      a = MFMA_BF16(kf1, qf[1], a, 0, 0, 0);
      s[jt][0] = a[0]; s[jt][1] = a[1]; s[jt][2] = a[2]; s[jt][3] = a[3];
    }
    __builtin_amdgcn_s_setprio(0);
    short8v vf0[4];
    {
      const int sl = ((jb * 8 + g) ^ (il & 7)) << 3;
#pragma unroll
      for (int ht = 0; ht < 4; ++ht)
        vf0[ht] = *(const short8v*)&sm[VT_OFF + (ht * 16 + il) * 256 + sl];
    }
#pragma unroll
    for (int jt = 0; jt < 4; ++jt) {
      if (SK && diag && (jt & 1)) continue;
      const int j0 = jb * 64 + ((jt & 1) << 5) + (g << 3) + ((jt >> 1) << 2);
#pragma unroll
      for (int r = 0; r < 4; ++r) {
        float pv = exp2f(s[jt][r]);
        if (diag && (j0 + r > i_row)) pv = 0.f;
        s[jt][r] = pv;
        lr += pv;
      }
    }
    short8v vf1[4];
    if (!(SK && diag)) {
      const int sl1 = ((jb * 8 + 4 + g) ^ (il & 7)) << 3;
#pragma unroll
      for (int ht = 0; ht < 4; ++ht)
        vf1[ht] = *(const short8v*)&sm[VT_OFF + (ht * 16 + il) * 256 + sl1];
    }
    __builtin_amdgcn_s_setprio(1);
    {
      short8v pf = mk8(pk2bf(s[0][0], s[0][1]), pk2bf(s[0][2], s[0][3]),
                       pk2bf(s[2][0], s[2][1]), pk2bf(s[2][2], s[2][3]));
#pragma unroll
      for (int ht = 0; ht < 4; ++ht)
        oa[ht] = MFMA_BF16(vf0[ht], pf, oa[ht], 0, 0, 0);
    }
    if (!(SK && diag)) {
      short8v pf = mk8(pk2bf(s[1][0], s[1][1]), pk2bf(s[1][2], s[1][3]),
                       pk2bf(s[3][0], s[3][1]), pk2bf(s[3][2], s[3][3]));
#pragma unroll
      for (int ht = 0; ht < 4; ++ht)
        oa[ht] = MFMA_BF16(vf1[ht], pf, oa[ht], 0, 0, 0);
    }
    __builtin_amdgcn_s_setprio(0);
  }
  lr += __shfl_xor(lr, 16);
  lr += __shfl_xor(lr, 32);
  const float inv = 1.f / lr;
#pragma unroll
  for (int ht = 0; ht < 4; ++ht) oa[ht] *= inv;
}

__global__ __launch_bounds__(512, 4) void head_fused(
    const float* __restrict__ x, const short* __restrict__ wt,
    float* __restrict__ out)
{
  extern __shared__ __align__(16) short sm[];
  const int b   = blockIdx.x;
  const int tid = threadIdx.x;
  const int w   = tid >> 6;
  const int l   = tid & 63;
  const int il  = l & 15;
  const int g   = l >> 4;

  int tqs[2]; tqs[0] = w; tqs[1] = 15 - w;   // balanced causal work

  // ---------- stage W^T -> LDS (coalesced 16B; slot XOR-swizzled by row&7) ----------
#pragma unroll
  for (int k = 0; k < 6; ++k) {
    int f   = tid + k * 512;          // 16B-slot index, 0..3071
    int row = f >> 4;
    int sl  = f & 15;
    short8v v = *(const short8v*)(wt + row * 128 + sl * 8);
    *(short8v*)&sm[row * 128 + ((sl ^ (row & 7)) << 3)] = v;
  }
  __syncthreads();

  // ---------- x load + convert (R10 verbatim) ----------
  short8v xa[2][4];
  {
    const float* xb = x + (size_t)b * (T_DIM * C_DIM);
#pragma unroll
    for (int tt = 0; tt < 2; ++tt)
#pragma unroll
      for (int ks = 0; ks < 4; ++ks) {
        const float* src = xb + (tqs[tt] * 16 + il) * C_DIM + ks * 32 + g * 8;
        float4v a0 = *(const float4v*)src;
        float4v a1 = *(const float4v*)(src + 4);
        xa[tt][ks] = mk8(pk2bf(a0.x, a0.y), pk2bf(a0.z, a0.w),
                         pk2bf(a1.x, a1.y), pk2bf(a1.z, a1.w));
      }
  }

  // W fragment from LDS: step idx covers wt rows idx*16 + il
  const int wkey = (il & 7);
#define WFRAG(idx, ks) \
  (*(const short8v*)&sm[((idx) * 16 + il) * 128 + ((((ks) * 4 + g) ^ wkey) << 3)])

  // ---------- phase 1: steps 0..7 (Q then K), W-frags from LDS ----------
  short8v qf[2][2];
  float4v accQ[2][4];
  short8v wb[2][4];
#pragma unroll
  for (int ks = 0; ks < 4; ++ks) wb[0][ks] = WFRAG(0, ks);
#pragma unroll
  for (int idx = 0; idx < 8; ++idx) {
    const int p   = idx >> 2, ht = idx & 3;
    const int cur = idx & 1,  nxt = cur ^ 1;
    {
      const int i2 = idx + 1;   // prefetch next step's W rows (V rows at idx==7: still live)
#pragma unroll
      for (int ks = 0; ks < 4; ++ks) wb[nxt][ks] = WFRAG(i2, ks);
    }
#pragma unroll
    for (int tt = 0; tt < 2; ++tt) {
      float4v acc = {0.f, 0.f, 0.f, 0.f};
      const int tq = tqs[tt];
      if (p == 0) {
        // Q^T = Wq^T_perm . x^T (W as A-frag) -> stays in registers
#pragma unroll
        for (int ks = 0; ks < 4; ++ks)
          acc = MFMA_BF16(wb[cur][ks], xa[tt][ks], acc, 0, 0, 0);
        accQ[tt][ht] = acc;
      } else {
#pragma unroll
        for (int ks = 0; ks < 4; ++ks)
          acc = MFMA_BF16(xa[tt][ks], wb[cur][ks], acc, 0, 0, 0);
        // K -> LDS, row-permuted: t = tq*16+g*4+r -> (t>>6)*64 + permrow(t&63)
        int row0 = (tq >> 2) * 64 + (((tq & 3) >> 1) + ((g & 1) << 1)) * 16
                 + (((((tq & 3) << 1) + (g >> 1)) & 3) << 2);
        int col = ht * 16 + il;
#pragma unroll
        for (int r = 0; r < 4; ++r)
          sm[K_OFF + kaddr(row0 + r, col)] = f2bf(acc[r]);
      }
    }
    if (idx == 3) {
#pragma unroll
      for (int tt = 0; tt < 2; ++tt)
#pragma unroll
        for (int hk = 0; hk < 2; ++hk)
          qf[tt][hk] = mk8(pk2bf(accQ[tt][hk][0],     accQ[tt][hk][1]),
                           pk2bf(accQ[tt][hk][2],     accQ[tt][hk][3]),
                           pk2bf(accQ[tt][hk + 2][0], accQ[tt][hk + 2][1]),
                           pk2bf(accQ[tt][hk + 2][2], accQ[tt][hk + 2][3]));
    }
  }
  // all waves done reading Q/K weight slabs before VT overwrites [0:16384)
  __syncthreads();

  // ---------- phase 1b: steps 8..11 (V), VT -> [0:16384) ----------
#pragma unroll
  for (int idx = 8; idx < 12; ++idx) {
    const int ht  = idx & 3;
    const int cur = idx & 1, nxt = cur ^ 1;
    if (idx < 11) {
#pragma unroll
      for (int ks = 0; ks < 4; ++ks) wb[nxt][ks] = WFRAG(idx + 1, ks);
    }
#pragma unroll
    for (int tt = 0; tt < 2; ++tt) {
      float4v acc = {0.f, 0.f, 0.f, 0.f};
#pragma unroll
      for (int ks = 0; ks < 4; ++ks)
        acc = MFMA_BF16(xa[tt][ks], wb[cur][ks], acc, 0, 0, 0);
      *(short4v*)&sm[VT_OFF + vaddr(ht * 16 + il, tqs[tt] * 16 + g * 4)] =
          mk4(pk2bf(acc[0], acc[1]), pk2bf(acc[2], acc[3]));
    }
  }
  __syncthreads();

  float* outb = out + (size_t)b * (T_DIM * H_DIM);

  // ---------- phase 2: attention + direct stores ----------
#pragma unroll
  for (int tt = 0; tt < 2; ++tt) {
    const int tq = tqs[tt];
    float4v oa[4];
#pragma unroll
    for (int ht = 0; ht < 4; ++ht) { float4v z = {0.f,0.f,0.f,0.f}; oa[ht] = z; }
    const bool sk = (tq & 3) < 2;
    if (tt == 0) {   // nb in {1,2}
      if (tq < 4) { if (sk) attn_tile<1, true>(sm, qf[0], il, g, tq, oa);
                    else    attn_tile<1, false>(sm, qf[0], il, g, tq, oa); }
      else        { if (sk) attn_tile<2, true>(sm, qf[0], il, g, tq, oa);
                    else    attn_tile<2, false>(sm, qf[0], il, g, tq, oa); }
    } else {         // nb in {3,4}
      if (tq < 12) { if (sk) attn_tile<3, true>(sm, qf[1], il, g, tq, oa);
                     else    attn_tile<3, false>(sm, qf[1], il, g, tq, oa); }
      else         { if (sk) attn_tile<4, true>(sm, qf[1], il, g, tq, oa);
                     else    attn_tile<4, false>(sm, qf[1], il, g, tq, oa); }
    }
    // direct stores: lane holds O[t = tq*16+il][h = ht*16 + g*4 .. +3]
#pragma unroll
    for (int ht = 0; ht < 4; ++ht)
      *(float4v*)&outb[(tq * 16 + il) * H_DIM + ht * 16 + g * 4] = oa[ht];
  }
}

extern "C" void kernel_launch(void* const* d_in, const int* in_sizes, int n_in,
                              void* d_out, int out_size, void* d_ws, size_t ws_size,
                              hipStream_t stream) {
  const float* x  = (const float*)d_in[0];
  const float* Wq = (const float*)d_in[1];
  const float* Wk = (const float*)d_in[2];
  const float* Wv = (const float*)d_in[3];
  float* out = (float*)d_out;
  short* wt = (short*)d_ws;   // 48 KB bf16 transposed weights
  prep_w<<<dim3(24), dim3(256), 0, stream>>>(Wq, Wk, Wv, wt);
  (void)hipFuncSetAttribute((const void*)head_fused,
                      hipFuncAttributeMaxDynamicSharedMemorySize, SMEM_BYTES);
  head_fused<<<dim3(1024), dim3(512), SMEM_BYTES, stream>>>(x, wt, out);
}